// Round 4
// baseline (191.205 us; speedup 1.0000x reference)
//
#include <hip/hip_runtime.h>
#include <hip/hip_bf16.h>
#include <stdint.h>

typedef unsigned short u16;
typedef __bf16 bf16x8 __attribute__((ext_vector_type(8)));
typedef float f32x4 __attribute__((ext_vector_type(4)));
typedef unsigned short u16x4 __attribute__((ext_vector_type(4)));

#define BM 128
#define BN 128
#define BK 32

__device__ inline float bf2f(u16 v) {
    return __builtin_bit_cast(float, (uint32_t)v << 16);
}
__device__ inline u16 f2bf(float v) {
    return __builtin_bit_cast(u16, (__bf16)v);
}
__device__ inline void cvt_store8(u16* dst, float4 v) {
    u16x4 o;
    o[0] = f2bf(v.x); o[1] = f2bf(v.y); o[2] = f2bf(v.z); o[3] = f2bf(v.w);
    *reinterpret_cast<u16x4*>(dst) = o;
}
__device__ inline void gll16(const void* src, const char* lds_dst) {
    __builtin_amdgcn_global_load_lds(
        (const __attribute__((address_space(1))) void*)src,
        (__attribute__((address_space(3))) void*)lds_dst, 16, 0, 0);
}

// XCD-bijective remap: dispatch-linear lin -> (bx,by) such that each XCD's
// dispatch chunk sweeps all by for consecutive bx (A-panel stays in its L2).
// Requires gridX%8==0 and total%8==0 (holds: 128x4, 128x16).
__device__ inline void xcd_remap(int nby, int& bx, int& by) {
    const int lin = (int)blockIdx.x + (int)blockIdx.y * (int)gridDim.x;
    const int g = lin & 7, s = lin >> 3;
    by = s % nby;
    bx = (s / nby) * 8 + g;
}

// ---------------------------------------------------------------------------
// GEMM1 fused: C[M][N](bf16) = A[M][K](f32, cvt in staging) @ Bt[N][K]^T(bf16)
// Double-buffered LDS, one barrier per K-step. A: reg-staged (issue early,
// ds_write late); B: global_load_lds into the next buffer.
// ---------------------------------------------------------------------------
__global__ __launch_bounds__(256) void gemm_xf32_bt(
    const float* __restrict__ A, const u16* __restrict__ Bt,
    u16* __restrict__ C, int M, int N, int K)
{
    __shared__ u16 Al[2][BM * BK];
    __shared__ u16 Bl[2][BN * BK];
    int bx, by; xcd_remap((int)gridDim.y, bx, by);

    const int tid  = threadIdx.x;
    const int wave = tid >> 6;
    const int lane = tid & 63;
    const int wr   = wave >> 1;
    const int wc   = wave & 1;

    // B staging map (global_load_lds 16B/thread, 2 rounds of 64 rows)
    const int srow = tid >> 2;
    const int skk  = (tid & 3) * 8;
    const u16* bbase0 = Bt + (long)(by * BN + srow) * K + skk;
    const u16* bbase1 = bbase0 + (long)64 * K;
    char* blds = (char*)&Bl[0][0];
    const int wslot = wave * 1024;

    // A reg-staging map: 4 float4/thread; round r covers rows r*32..r*32+31
    const int arow = tid >> 3;        // 0..31
    const int akk  = (tid & 7) * 4;   // 0,4,...,28
    const float* abase = A + (long)(bx * BM + arow) * K + akk;
    const long arstr = (long)32 * K;
    const int awoff = arow * BK + akk;

    f32x4 acc[4][4];
#pragma unroll
    for (int i = 0; i < 4; ++i)
#pragma unroll
        for (int j = 0; j < 4; ++j) acc[i][j] = (f32x4){0.f, 0.f, 0.f, 0.f};

    const int fr  = lane & 15;
    const int fk  = (lane >> 4) * 8;
    const int aoff = (wr * 64 + fr) * BK + fk;
    const int boff = (wc * 64 + fr) * BK + fk;

    const int NT = K / BK;

    // ---- prologue: stage tile 0 into buffer 0 ----
    {
        gll16(bbase0, blds + wslot);
        gll16(bbase1, blds + 4096 + wslot);
        float4 p0 = *(const float4*)(abase);
        float4 p1 = *(const float4*)(abase + arstr);
        float4 p2 = *(const float4*)(abase + 2 * arstr);
        float4 p3 = *(const float4*)(abase + 3 * arstr);
        cvt_store8(&Al[0][awoff + 0 * 32 * BK], p0);
        cvt_store8(&Al[0][awoff + 1 * 32 * BK], p1);
        cvt_store8(&Al[0][awoff + 2 * 32 * BK], p2);
        cvt_store8(&Al[0][awoff + 3 * 32 * BK], p3);
        __syncthreads();
    }

    for (int t = 0; t < NT; ++t) {
        const int cur = t & 1, nxt = cur ^ 1;
        // clamped next-tile k (last iter restages tile 0; never read)
        const int ktn = (t + 1 < NT) ? (t + 1) * BK : 0;

        // issue next A loads (consumed after MFMA -> latency hidden)
        const float* an = abase + ktn;
        float4 p0 = *(const float4*)(an);
        float4 p1 = *(const float4*)(an + arstr);
        float4 p2 = *(const float4*)(an + 2 * arstr);
        float4 p3 = *(const float4*)(an + 3 * arstr);
        // issue next B staging into the other buffer
        gll16(bbase0 + ktn, blds + nxt * 8192 + wslot);
        gll16(bbase1 + ktn, blds + nxt * 8192 + 4096 + wslot);

        // compute on current buffer
        bf16x8 af[4], bfg[4];
#pragma unroll
        for (int m = 0; m < 4; ++m)
            af[m] = *(const bf16x8*)&Al[cur][aoff + m * 16 * BK];
#pragma unroll
        for (int n = 0; n < 4; ++n)
            bfg[n] = *(const bf16x8*)&Bl[cur][boff + n * 16 * BK];
#pragma unroll
        for (int m = 0; m < 4; ++m)
#pragma unroll
            for (int n = 0; n < 4; ++n)
                acc[m][n] = __builtin_amdgcn_mfma_f32_16x16x32_bf16(
                    af[m], bfg[n], acc[m][n], 0, 0, 0);

        // write next A into the other buffer (vmcnt wait lands here, after MFMA)
        cvt_store8(&Al[nxt][awoff + 0 * 32 * BK], p0);
        cvt_store8(&Al[nxt][awoff + 1 * 32 * BK], p1);
        cvt_store8(&Al[nxt][awoff + 2 * 32 * BK], p2);
        cvt_store8(&Al[nxt][awoff + 3 * 32 * BK], p3);
        __syncthreads();   // drains B-staging + makes A-writes visible
    }

    const int crow = bx * BM + wr * 64 + (lane >> 4) * 4;
    const int ccol = by * BN + wc * 64 + (lane & 15);
#pragma unroll
    for (int m = 0; m < 4; ++m)
#pragma unroll
        for (int n = 0; n < 4; ++n)
#pragma unroll
            for (int j = 0; j < 4; ++j)
                C[(long)(crow + m * 16 + j) * N + (ccol + n * 16)] =
                    f2bf(acc[m][n][j]);
}

// ---------------------------------------------------------------------------
// GEMM2: C[M][N](f32) = A[M][K](bf16) @ Bt[N][K]^T(bf16)
// Double-buffered LDS, one barrier per K-step, both operands global_load_lds.
// ---------------------------------------------------------------------------
__global__ __launch_bounds__(256) void gemm_bt(
    const u16* __restrict__ A, const u16* __restrict__ Bt,
    float* __restrict__ C, int M, int N, int K)
{
    __shared__ u16 Al[2][BM * BK];
    __shared__ u16 Bl[2][BN * BK];
    int bx, by; xcd_remap((int)gridDim.y, bx, by);

    const int tid  = threadIdx.x;
    const int wave = tid >> 6;
    const int lane = tid & 63;
    const int wr   = wave >> 1;
    const int wc   = wave & 1;

    const int srow = tid >> 2;
    const int skk  = (tid & 3) * 8;

    const u16* abase0 = A + (long)(bx * BM + srow) * K + skk;
    const u16* abase1 = abase0 + (long)64 * K;
    const u16* bbase0 = Bt + (long)(by * BN + srow) * K + skk;
    const u16* bbase1 = bbase0 + (long)64 * K;

    char* alds = (char*)&Al[0][0];
    char* blds = (char*)&Bl[0][0];
    const int wslot = wave * 1024;

    f32x4 acc[4][4];
#pragma unroll
    for (int i = 0; i < 4; ++i)
#pragma unroll
        for (int j = 0; j < 4; ++j) acc[i][j] = (f32x4){0.f, 0.f, 0.f, 0.f};

    const int fr  = lane & 15;
    const int fk  = (lane >> 4) * 8;
    const int aoff = (wr * 64 + fr) * BK + fk;
    const int boff = (wc * 64 + fr) * BK + fk;

    const int NT = K / BK;

    // prologue: stage tile 0 into buffer 0
    gll16(abase0, alds + wslot);
    gll16(abase1, alds + 4096 + wslot);
    gll16(bbase0, blds + wslot);
    gll16(bbase1, blds + 4096 + wslot);
    __syncthreads();

    for (int t = 0; t < NT; ++t) {
        const int cur = t & 1, nxt = cur ^ 1;
        const int ktn = (t + 1 < NT) ? (t + 1) * BK : 0;

        // stage next tile into the other buffer (flies during MFMA)
        gll16(abase0 + ktn, alds + nxt * 8192 + wslot);
        gll16(abase1 + ktn, alds + nxt * 8192 + 4096 + wslot);
        gll16(bbase0 + ktn, blds + nxt * 8192 + wslot);
        gll16(bbase1 + ktn, blds + nxt * 8192 + 4096 + wslot);

        bf16x8 af[4], bfg[4];
#pragma unroll
        for (int m = 0; m < 4; ++m)
            af[m] = *(const bf16x8*)&Al[cur][aoff + m * 16 * BK];
#pragma unroll
        for (int n = 0; n < 4; ++n)
            bfg[n] = *(const bf16x8*)&Bl[cur][boff + n * 16 * BK];
#pragma unroll
        for (int m = 0; m < 4; ++m)
#pragma unroll
            for (int n = 0; n < 4; ++n)
                acc[m][n] = __builtin_amdgcn_mfma_f32_16x16x32_bf16(
                    af[m], bfg[n], acc[m][n], 0, 0, 0);

        __syncthreads();   // next tile staged + current reads done
    }

    const int crow = bx * BM + wr * 64 + (lane >> 4) * 4;
    const int ccol = by * BN + wc * 64 + (lane & 15);
#pragma unroll
    for (int m = 0; m < 4; ++m)
#pragma unroll
        for (int n = 0; n < 4; ++n)
#pragma unroll
            for (int j = 0; j < 4; ++j)
                C[(long)(crow + m * 16 + j) * N + (ccol + n * 16)] = acc[m][n][j];
}

// ---------------------------------------------------------------------------
// fused 3-layer EMA scan over l, chunked with zero-state lookback.
// SCHUNK=64, LOOK=256; double-buffered 8-deep register prefetch.
// ---------------------------------------------------------------------------
#define SCHUNK 64
#define SLOOK  256

__device__ inline float sigmoidf_(float x) { return 1.f / (1.f + __expf(-x)); }

__global__ __launch_bounds__(256) void ema3_scan_bf(
    const u16* __restrict__ h, const float* __restrict__ log_a,
    u16* __restrict__ h3)
{
    const int t = (int)blockIdx.x * 256 + (int)threadIdx.x;  // 131072 threads
    const int e     = t & 511;
    const int b     = (t >> 9) & 3;
    const int chunk = t >> 11;           // 0..63
    const float a1 = sigmoidf_(log_a[e]);
    const float a2 = sigmoidf_(log_a[512 + e]);
    const float a3 = sigmoidf_(log_a[1024 + e]);
    const float c1 = 1.f - a1, c2 = 1.f - a2, c3 = 1.f - a3;
    const long base = ((long)b * 4096) * 512 + e;
    const int l0 = chunk * SCHUNK;
    const int ls = (l0 - SLOOK > 0) ? (l0 - SLOOK) : 0;
    const int S  = l0 + SCHUNK - ls;     // 64..320, all /16
    const u16* hp = h + base + (long)ls * 512;
    u16* op = h3 + base + (long)ls * 512;
    int gl = ls;
    float y1 = 0.f, y2 = 0.f, y3 = 0.f;

    u16 A[8], B[8];
#pragma unroll
    for (int i = 0; i < 8; ++i) A[i] = hp[(long)i * 512];
    hp += 8 * 512;

    const int nb = S >> 4;
    for (int ib = 0; ib < nb; ++ib) {
#pragma unroll
        for (int i = 0; i < 8; ++i) B[i] = hp[(long)i * 512];
        hp += 8 * 512;
#pragma unroll
        for (int i = 0; i < 8; ++i) {
            const float v = bf2f(A[i]);
            y1 = a1 * y1 + c1 * v;
            y2 = a2 * y2 + c2 * y1;
            y3 = a3 * y3 + c3 * y2;
            if (gl >= l0) *op = f2bf(y3);
            op += 512; ++gl;
        }
        // over-reads up to 8 rows past chunk end (in-bounds: h sits at
        // d_out+64MiB inside the 128MiB region; values never consumed)
#pragma unroll
        for (int i = 0; i < 8; ++i) A[i] = hp[(long)i * 512];
        hp += 8 * 512;
#pragma unroll
        for (int i = 0; i < 8; ++i) {
            const float v = bf2f(B[i]);
            y1 = a1 * y1 + c1 * v;
            y2 = a2 * y2 + c2 * y1;
            y3 = a3 * y3 + c3 * y2;
            if (gl >= l0) *op = f2bf(y3);
            op += 512; ++gl;
        }
    }
}

// ---------------------------------------------------------------------------
// both weight matrices f32 -> bf16 in one launch (1M f32 each)
// ---------------------------------------------------------------------------
__global__ __launch_bounds__(256) void cvt_weights(
    const float* __restrict__ wd, const float* __restrict__ wu,
    u16* __restrict__ wd_o, u16* __restrict__ wu_o, int n4each)
{
    int i = (int)blockIdx.x * 256 + (int)threadIdx.x;
    const int stride = (int)gridDim.x * 256;
    for (; i < 2 * n4each; i += stride) {
        const float* in = (i < n4each) ? wd : wu;
        u16* out = (i < n4each) ? wd_o : wu_o;
        const int j = (i < n4each) ? i : (i - n4each);
        const float4 v = reinterpret_cast<const float4*>(in)[j];
        u16x4 o;
        o[0] = f2bf(v.x); o[1] = f2bf(v.y); o[2] = f2bf(v.z); o[3] = f2bf(v.w);
        reinterpret_cast<u16x4*>(out)[j] = o;
    }
}

// ---------------------------------------------------------------------------
// B=4, L=4096, D=2048, Di=512. Scratch plan:
//   d_out[64:80MiB)  = h (bf16)    (dead before GEMM2 writes d_out)
//   d_ws[0:2MiB)     = W_down bf16
//   d_ws[2:4MiB)     = W_up   bf16
//   d_ws[4:20MiB)    = h3 bf16
// ---------------------------------------------------------------------------
extern "C" void kernel_launch(void* const* d_in, const int* in_sizes, int n_in,
                              void* d_out, int out_size, void* d_ws, size_t ws_size,
                              hipStream_t stream)
{
    const float* x      = (const float*)d_in[0];
    const float* W_down = (const float*)d_in[1];
    const float* W_up   = (const float*)d_in[2];
    const float* log_a  = (const float*)d_in[3];
    float* out = (float*)d_out;

    u16*   h_bf  = (u16*)((char*)d_out + (64u << 20));
    u16*   Wd_bf = (u16*)d_ws;
    u16*   Wu_bf = (u16*)((char*)d_ws + (2u << 20));
    u16*   h3    = (u16*)((char*)d_ws + (4u << 20));

    cvt_weights<<<512, 256, 0, stream>>>(W_down, W_up, Wd_bf, Wu_bf,
                                         (512 * 2048) / 4);

    // h = x @ W_down^T   (M=16384, N=512, K=2048), f32 A converted in staging
    gemm_xf32_bt<<<dim3(128, 4), 256, 0, stream>>>(x, Wd_bf, h_bf, 16384, 512, 2048);

    // 3-layer EMA scan, bf16 in/out
    ema3_scan_bf<<<512, 256, 0, stream>>>(h_bf, log_a, h3);

    // out = h3 @ W_up^T  (M=16384, N=2048, K=512), f32 out
    gemm_bt<<<dim3(128, 16), 256, 0, stream>>>(h3, Wu_bf, out, 16384, 2048, 512);
}